// Round 4
// baseline (593.479 us; speedup 1.0000x reference)
//
#include <hip/hip_runtime.h>
#include <math.h>

#define NB 1024

typedef __bf16 mbf8 __attribute__((ext_vector_type(8)));
typedef float  mf4  __attribute__((ext_vector_type(4)));

union Pk { __bf16 h[4]; uint2 u2; };

__device__ __forceinline__ mf4 mfma16(mbf8 a, mbf8 b, mf4 c) {
  return __builtin_amdgcn_mfma_f32_16x16x32_bf16(a, b, c, 0, 0, 0);
}

__device__ __forceinline__ float dot4f(float4 a, float4 b){
  return a.x*b.x + a.y*b.y + a.z*b.z + a.w*b.w;
}

__device__ __forceinline__ mbf8 ld_frag_f32(const float* p) {
  float4 u0 = *(const float4*)p;
  float4 u1 = *(const float4*)(p + 4);
  mbf8 v;
  v[0]=(__bf16)u0.x; v[1]=(__bf16)u0.y; v[2]=(__bf16)u0.z; v[3]=(__bf16)u0.w;
  v[4]=(__bf16)u1.x; v[5]=(__bf16)u1.y; v[6]=(__bf16)u1.z; v[7]=(__bf16)u1.w;
  return v;
}

__device__ __forceinline__ mbf8 zero8() {
  mbf8 v;
  #pragma unroll
  for (int q = 0; q < 8; ++q) v[q] = (__bf16)0.f;
  return v;
}

// ---------------- prep: fp32 weights -> bf16 MFMA fragments in ws ----------------
__global__ __launch_bounds__(256) void prep_kernel(
    const float* __restrict__ xw1, const float* __restrict__ f1w1, const float* __restrict__ f2w1,
    const float* __restrict__ xw2, const float* __restrict__ f1w2, const float* __restrict__ f2w2,
    const float* __restrict__ d1w, const float* __restrict__ d2w, const float* __restrict__ d3w,
    __bf16* __restrict__ out)
{
  int idx = blockIdx.x * 256 + threadIdx.x;
  if (idx >= 693248) return;
  int which, local;
  if (idx < 10240)       { which = 0; local = idx; }
  else if (idx < 272384) { which = 1; local = idx - 10240; }
  else if (idx < 403456) { which = 2; local = idx - 272384; }
  else if (idx < 413696) { which = 3; local = idx - 403456; }
  else if (idx < 544768) { which = 4; local = idx - 413696; }
  else if (idx < 610304) { which = 5; local = idx - 544768; }
  else if (idx < 675840) { which = 6; local = idx - 610304; }
  else if (idx < 692224) { which = 7; local = idx - 675840; }
  else                   { which = 8; local = idx - 692224; }
  int tile = local >> 9, r = local & 511, lane = r >> 3, j = r & 7;
  int quad = lane >> 4, lm = lane & 15, khi = quad * 8 + j;
  float val = 0.f;
  switch (which) {
    case 0: { int k = tile*32 + khi; val = xw1[lm*640 + k]; } break;
    case 1: { int L = tile >> 7, nt = tile & 127, n = nt*16 + lm;
              val = (khi < 16) ? f1w1[(L*2048 + n)*16 + khi] : 0.f; } break;
    case 2: { int L = tile >> 6, ks = tile & 63, k = ks*32 + khi;
              val = f2w1[(L*16 + lm)*2048 + k]; } break;
    case 3: { int k = tile*32 + khi; val = (lm < 8) ? xw2[lm*640 + k] : 0.f; } break;
    case 4: { int L = tile >> 7, nt = tile & 127, n = nt*16 + lm;
              val = (khi < 8) ? f1w2[(L*2048 + n)*8 + khi] : 0.f; } break;
    case 5: { int L = tile >> 6, ks = tile & 63, k = ks*32 + khi;
              val = (lm < 8) ? f2w2[(L*8 + lm)*2048 + k] : 0.f; } break;
    case 6: { int nt = tile >> 3, ks = tile & 7, k = ks*32 + khi;
              val = (k < 253) ? d1w[(nt*16 + lm)*253 + k] : 0.f; } break;
    case 7: { int nt = tile >> 3, ks = tile & 7, k = ks*32 + khi;
              val = d2w[(nt*16 + lm)*256 + k]; } break;
    default:{ int ks = tile, k = ks*32 + khi;
              val = d3w[lm*64 + k]; } break;
  }
  out[idx] = (__bf16)val;
}

// ---------------- Branch 1 body: siRNA, S=21, D=16, H=2, L=4 ----------------
__device__ __forceinline__ void run_b1(int b, float* smem,
    const float* __restrict__ inp, const float* __restrict__ xb,
    const float* __restrict__ qw, const float* __restrict__ qb,
    const float* __restrict__ ow, const float* __restrict__ ob,
    const float* __restrict__ f1b, const float* __restrict__ f2b,
    const float* __restrict__ g1w, const float* __restrict__ b1w,
    const float* __restrict__ g2w, const float* __restrict__ b2w,
    const float* __restrict__ ymw, const float* __restrict__ ymb,
    const __bf16* __restrict__ xwB, const __bf16* __restrict__ w1B,
    const __bf16* __restrict__ w2B, float* __restrict__ outp)
{
  float* xs  = smem;          // [21][20]
  float* xr  = smem + 420;
  float* ao  = smem + 840;
  float* pool= smem + 1264;   // 4288 floats: qkv(1092)+sc(966) | red(2176) | hbuf(32*268 bf16)
  float* mu  = smem + 5552;
  float* rsd = smem + 5573;

  const int tid = threadIdx.x;
  const int w = tid >> 6, lane = tid & 63, quad = lane >> 4, lm = lane & 15;
  float* qkv = pool;
  float* sc  = pool + 1092;   // [42][23]
  float* red = pool;          // [8][16][17]
  __bf16* hbuf = (__bf16*)pool; // [32][268]
  const float* Ain = inp + (size_t)b * 21 * 640;

  // ---- input projection via MFMA ----
  mf4 pc0 = {0.f,0.f,0.f,0.f}, pc1 = {0.f,0.f,0.f,0.f};
  for (int i = 0; i < 5; ++i) {
    int ks = w*5 + i;
    mbf8 bv = *(const mbf8*)(xwB + (ks*64 + lane)*8);
    #pragma unroll
    for (int mt = 0; mt < 2; ++mt) {
      int row = mt*16 + lm; row = row > 20 ? 20 : row;
      mbf8 av = ld_frag_f32(Ain + row*640 + ks*32 + quad*8);
      if (mt == 0) pc0 = mfma16(av, bv, pc0); else pc1 = mfma16(av, bv, pc1);
    }
  }
  #pragma unroll
  for (int r = 0; r < 4; ++r) {
    red[((w*2+0)*16 + quad*4 + r)*17 + lm] = pc0[r];
    red[((w*2+1)*16 + quad*4 + r)*17 + lm] = pc1[r];
  }
  __syncthreads();
  {
    const float lf = -logf(10000.0f) / 16.0f;
    for (int idx = tid; idx < 336; idx += 256) {
      int t = idx >> 4, i = idx & 15, mt = t >> 4, tl = t & 15;
      float s = red[((0+mt)*16+tl)*17+i] + red[((2+mt)*16+tl)*17+i]
              + red[((4+mt)*16+tl)*17+i] + red[((6+mt)*16+tl)*17+i];
      float freq = expf((float)((i>>1)*2) * lf);
      float pe = (i & 1) ? cosf((float)t * freq) : sinf((float)t * freq);
      xs[t*20 + i] = s + xb[i] + pe;
    }
  }
  __syncthreads();

  for (int L = 0; L < 4; ++L) {
    for (int idx = tid; idx < 1008; idx += 256) {
      int s = idx / 48, e = idx % 48;
      const float* wr = qw + (L*48 + e)*16;
      float a = qb[L*48 + e];
      #pragma unroll
      for (int k = 0; k < 16; ++k) a += xs[s*20+k] * wr[k];
      qkv[s*52 + e] = a;
    }
    __syncthreads();

    { // scores via MFMA: wave w -> (h=w>>1, mt=w&1), nt=0..1
      int h = w >> 1, mt = w & 1;
      mbf8 qf = zero8();
      if (quad == 0) {
        int tok = mt*16 + lm; tok = tok > 20 ? 20 : tok;
        const float* p = qkv + tok*52 + h*8;
        #pragma unroll
        for (int j = 0; j < 8; ++j) qf[j] = (__bf16)(p[j] * 0.35355339059327373f);
      }
      #pragma unroll
      for (int nt = 0; nt < 2; ++nt) {
        mbf8 kf = zero8();
        if (quad == 0) {
          int key = nt*16 + lm; key = key > 20 ? 20 : key;
          const float* p = qkv + key*52 + 16 + h*8;
          #pragma unroll
          for (int j = 0; j < 8; ++j) kf[j] = (__bf16)p[j];
        }
        mf4 z = {0.f,0.f,0.f,0.f};
        mf4 c = mfma16(qf, kf, z);
        #pragma unroll
        for (int r = 0; r < 4; ++r) {
          int row = mt*16 + quad*4 + r, col = nt*16 + lm;
          if (row < 21 && col < 21) sc[(h*21 + row)*23 + col] = c[r];
        }
      }
    }
    __syncthreads();

    { // softmax: 4 threads per row
      int r = tid >> 2, p = tid & 3;
      if (r < 42) {
        float* row = sc + r*23;
        float m = -1e30f;
        for (int j = p; j < 21; j += 4) m = fmaxf(m, row[j]);
        m = fmaxf(m, __shfl_xor(m, 1));
        m = fmaxf(m, __shfl_xor(m, 2));
        float ssum = 0.f;
        for (int j = p; j < 21; j += 4) { float e = __expf(row[j] - m); row[j] = e; ssum += e; }
        ssum += __shfl_xor(ssum, 1);
        ssum += __shfl_xor(ssum, 2);
        float inv = 1.f / ssum;
        for (int j = p; j < 21; j += 4) row[j] *= inv;
      }
    }
    __syncthreads();

    { // P·V via MFMA: wave w -> (h, mt); K=32 covers 21 keys
      int h = w >> 1, mt = w & 1;
      mbf8 pf = zero8(), vf = zero8();
      {
        int tok = mt*16 + lm;
        #pragma unroll
        for (int j = 0; j < 8; ++j) {
          int k = quad*8 + j;
          pf[j] = (__bf16)((tok < 21 && k < 21) ? sc[(h*21 + tok)*23 + k] : 0.f);
          vf[j] = (__bf16)((lm < 8 && k < 21) ? qkv[k*52 + 32 + h*8 + lm] : 0.f);
        }
      }
      mf4 z = {0.f,0.f,0.f,0.f};
      mf4 c = mfma16(pf, vf, z);
      #pragma unroll
      for (int r = 0; r < 4; ++r) {
        int tok = mt*16 + quad*4 + r;
        if (tok < 21 && lm < 8) ao[tok*20 + h*8 + lm] = c[r];
      }
    }
    __syncthreads();

    for (int idx = tid; idx < 336; idx += 256) {
      int s = idx >> 4, i = idx & 15;
      const float* wr = ow + (L*16 + i)*16;
      float a = ob[L*16 + i];
      #pragma unroll
      for (int c = 0; c < 16; ++c) a += ao[s*20 + c] * wr[c];
      xr[s*20 + i] = xs[s*20 + i] + a;
    }
    __syncthreads();

    if (tid < 21) {
      float m = 0.f;
      #pragma unroll
      for (int k = 0; k < 16; ++k) m += xr[tid*20 + k];
      m *= (1.f/16.f);
      float v = 0.f;
      #pragma unroll
      for (int k = 0; k < 16; ++k) { float d = xr[tid*20 + k] - m; v += d*d; }
      v *= (1.f/16.f);
      mu[tid] = m; rsd[tid] = rsqrtf(v + 1e-5f);
    }
    __syncthreads();
    for (int idx = tid; idx < 336; idx += 256) {
      int s = idx >> 4, i = idx & 15;
      xs[s*20 + i] = (xr[s*20 + i] - mu[s]) * rsd[s] * g1w[L*16+i] + b1w[L*16+i];
    }
    __syncthreads();

    // ---- FFN via MFMA ----
    mbf8 xf0 = zero8(), xf1 = zero8();
    if (quad < 2) {
      int t0 = lm;
      int t1 = 16 + lm; if (t1 > 20) t1 = 20;
      xf0 = ld_frag_f32(xs + t0*20 + quad*8);
      xf1 = ld_frag_f32(xs + t1*20 + quad*8);
    }
    mf4 of0 = {0.f,0.f,0.f,0.f}, of1 = {0.f,0.f,0.f,0.f};
    const __bf16* w1L = w1B + (size_t)L*128*512;
    const __bf16* w2L = w2B + (size_t)L*64*512;
    const float* f1bL = f1b + L*2048;
    for (int ci = 0; ci < 8; ++ci) {
      #pragma unroll
      for (int u = 0; u < 4; ++u) {
        int ut = ci*16 + w*4 + u;
        mbf8 wa = *(const mbf8*)(w1L + (ut*64 + lane)*8);
        float4 bia = *(const float4*)(f1bL + ut*16 + quad*4);
        mf4 z = {0.f,0.f,0.f,0.f};
        mf4 c0 = mfma16(wa, xf0, z);
        mf4 c1 = mfma16(wa, xf1, z);
        Pk p0, p1;
        p0.h[0]=(__bf16)fmaxf(c0[0]+bia.x,0.f); p0.h[1]=(__bf16)fmaxf(c0[1]+bia.y,0.f);
        p0.h[2]=(__bf16)fmaxf(c0[2]+bia.z,0.f); p0.h[3]=(__bf16)fmaxf(c0[3]+bia.w,0.f);
        p1.h[0]=(__bf16)fmaxf(c1[0]+bia.x,0.f); p1.h[1]=(__bf16)fmaxf(c1[1]+bia.y,0.f);
        p1.h[2]=(__bf16)fmaxf(c1[2]+bia.z,0.f); p1.h[3]=(__bf16)fmaxf(c1[3]+bia.w,0.f);
        int colb = (ut & 15)*16 + quad*4;
        *(uint2*)(hbuf + lm*268 + colb)        = p0.u2;
        *(uint2*)(hbuf + (16 + lm)*268 + colb) = p1.u2;
      }
      #pragma unroll
      for (int kk = 0; kk < 2; ++kk) {
        int ksl = w*2 + kk;
        mbf8 wb = *(const mbf8*)(w2L + ((ci*8 + ksl)*64 + lane)*8);
        mbf8 a0 = *(const mbf8*)(hbuf + lm*268 + ksl*32 + quad*8);
        mbf8 a1 = *(const mbf8*)(hbuf + (16 + lm)*268 + ksl*32 + quad*8);
        of0 = mfma16(a0, wb, of0);
        of1 = mfma16(a1, wb, of1);
      }
    }
    __syncthreads();
    #pragma unroll
    for (int r = 0; r < 4; ++r) {
      red[((w*2+0)*16 + quad*4 + r)*17 + lm] = of0[r];
      red[((w*2+1)*16 + quad*4 + r)*17 + lm] = of1[r];
    }
    __syncthreads();
    for (int idx = tid; idx < 336; idx += 256) {
      int t = idx >> 4, i = idx & 15, mt = t >> 4, tl = t & 15;
      float s = red[((0+mt)*16+tl)*17+i] + red[((2+mt)*16+tl)*17+i]
              + red[((4+mt)*16+tl)*17+i] + red[((6+mt)*16+tl)*17+i];
      xr[t*20 + i] = xs[t*20 + i] + s + f2b[L*16 + i];
    }
    __syncthreads();
    if (tid < 21) {
      float m = 0.f;
      #pragma unroll
      for (int k = 0; k < 16; ++k) m += xr[tid*20 + k];
      m *= (1.f/16.f);
      float v = 0.f;
      #pragma unroll
      for (int k = 0; k < 16; ++k) { float d = xr[tid*20 + k] - m; v += d*d; }
      v *= (1.f/16.f);
      mu[tid] = m; rsd[tid] = rsqrtf(v + 1e-5f);
    }
    __syncthreads();
    for (int idx = tid; idx < 336; idx += 256) {
      int s = idx >> 4, i = idx & 15;
      xs[s*20 + i] = (xr[s*20 + i] - mu[s]) * rsd[s] * g2w[L*16+i] + b2w[L*16+i];
    }
    __syncthreads();
  }

  for (int idx = tid; idx < 84; idx += 256) {
    int s = idx >> 2, j = idx & 3;
    float a = ymb[j];
    #pragma unroll
    for (int k = 0; k < 16; ++k) a += xs[s*20 + k] * ymw[j*16 + k];
    outp[(size_t)b*84 + idx] = a;
  }
}

// ---------------- Branch 2 body: mRNA, S=59, D=8, H=1, L=2 ----------------
__device__ __forceinline__ void run_b2(int b, float* smem,
    const float* __restrict__ inp, const float* __restrict__ xb,
    const float* __restrict__ qw, const float* __restrict__ qb,
    const float* __restrict__ ow, const float* __restrict__ ob,
    const float* __restrict__ f1b, const float* __restrict__ f2b,
    const float* __restrict__ g1w, const float* __restrict__ b1w,
    const float* __restrict__ g2w, const float* __restrict__ b2w,
    const float* __restrict__ ymw, const float* __restrict__ ymb,
    const __bf16* __restrict__ xwB, const __bf16* __restrict__ w1B,
    const __bf16* __restrict__ w2B, float* __restrict__ outp)
{
  float* xs  = smem;          // [59][12]
  float* xr  = smem + 708;
  float* ao  = smem + 1416;
  float* pool= smem + 2124;   // 5251 floats: qkv(1652)+sc(3599) | red(4352) | hbuf(64*140 bf16)
  float* mu  = smem + 7375;
  float* rsd = smem + 7434;

  const int tid = threadIdx.x;
  const int w = tid >> 6, lane = tid & 63, quad = lane >> 4, lm = lane & 15;
  float* qkv = pool;          // [59][28]
  float* sc  = pool + 1652;   // [59][61]
  float* red = pool;          // [16][16][17]
  __bf16* hbuf = (__bf16*)pool; // [64][140]
  const float* Ain = inp + (size_t)b * 59 * 640;

  mf4 pc[4];
  #pragma unroll
  for (int mt = 0; mt < 4; ++mt) { mf4 z = {0.f,0.f,0.f,0.f}; pc[mt] = z; }
  for (int i = 0; i < 5; ++i) {
    int ks = w*5 + i;
    mbf8 bv = *(const mbf8*)(xwB + (ks*64 + lane)*8);
    #pragma unroll
    for (int mt = 0; mt < 4; ++mt) {
      int row = mt*16 + lm; row = row > 58 ? 58 : row;
      mbf8 av = ld_frag_f32(Ain + row*640 + ks*32 + quad*8);
      pc[mt] = mfma16(av, bv, pc[mt]);
    }
  }
  #pragma unroll
  for (int mt = 0; mt < 4; ++mt)
    #pragma unroll
    for (int r = 0; r < 4; ++r)
      red[((w*4+mt)*16 + quad*4 + r)*17 + lm] = pc[mt][r];
  __syncthreads();
  {
    const float lf = -logf(10000.0f) / 8.0f;
    for (int idx = tid; idx < 472; idx += 256) {
      int t = idx >> 3, i = idx & 7, mt = t >> 4, tl = t & 15;
      float s = red[((0*4+mt)*16+tl)*17+i] + red[((1*4+mt)*16+tl)*17+i]
              + red[((2*4+mt)*16+tl)*17+i] + red[((3*4+mt)*16+tl)*17+i];
      float freq = expf((float)((i>>1)*2) * lf);
      float pe = (i & 1) ? cosf((float)t * freq) : sinf((float)t * freq);
      xs[t*12 + i] = s + xb[i] + pe;
    }
  }
  __syncthreads();

  for (int L = 0; L < 2; ++L) {
    for (int idx = tid; idx < 1416; idx += 256) {
      int s = idx / 24, e = idx % 24;
      const float* wr = qw + (L*24 + e)*8;
      float a = qb[L*24 + e];
      #pragma unroll
      for (int k = 0; k < 8; ++k) a += xs[s*12+k] * wr[k];
      qkv[s*28 + e] = a;
    }
    __syncthreads();

    { // scores via MFMA: wave w = m-tile, nt = 0..3
      mbf8 qf = zero8();
      if (quad == 0) {
        int tok = w*16 + lm; tok = tok > 58 ? 58 : tok;
        const float* p = qkv + tok*28;
        #pragma unroll
        for (int j = 0; j < 8; ++j) qf[j] = (__bf16)(p[j] * 0.35355339059327373f);
      }
      #pragma unroll
      for (int nt = 0; nt < 4; ++nt) {
        mbf8 kf = zero8();
        if (quad == 0) {
          int key = nt*16 + lm; key = key > 58 ? 58 : key;
          const float* p = qkv + key*28 + 8;
          #pragma unroll
          for (int j = 0; j < 8; ++j) kf[j] = (__bf16)p[j];
        }
        mf4 z = {0.f,0.f,0.f,0.f};
        mf4 c = mfma16(qf, kf, z);
        #pragma unroll
        for (int r = 0; r < 4; ++r) {
          int row = w*16 + quad*4 + r, col = nt*16 + lm;
          if (row < 59 && col < 59) sc[row*61 + col] = c[r];
        }
      }
    }
    __syncthreads();

    { // softmax: 4 threads per row
      int r = tid >> 2, p = tid & 3;
      if (r < 59) {
        float* row = sc + r*61;
        float m = -1e30f;
        for (int j = p; j < 59; j += 4) m = fmaxf(m, row[j]);
        m = fmaxf(m, __shfl_xor(m, 1));
        m = fmaxf(m, __shfl_xor(m, 2));
        float ssum = 0.f;
        for (int j = p; j < 59; j += 4) { float e = __expf(row[j] - m); row[j] = e; ssum += e; }
        ssum += __shfl_xor(ssum, 1);
        ssum += __shfl_xor(ssum, 2);
        float inv = 1.f / ssum;
        for (int j = p; j < 59; j += 4) row[j] *= inv;
      }
    }
    __syncthreads();

    { // P·V via MFMA: wave w = m-tile; K split 2x32 over 59 keys
      mf4 acc = {0.f,0.f,0.f,0.f};
      #pragma unroll
      for (int kk = 0; kk < 2; ++kk) {
        mbf8 pf = zero8(), vf = zero8();
        int tok = w*16 + lm;
        #pragma unroll
        for (int j = 0; j < 8; ++j) {
          int k = kk*32 + quad*8 + j;
          pf[j] = (__bf16)((tok < 59 && k < 59) ? sc[tok*61 + k] : 0.f);
          vf[j] = (__bf16)((lm < 8 && k < 59) ? qkv[k*28 + 16 + lm] : 0.f);
        }
        acc = mfma16(pf, vf, acc);
      }
      #pragma unroll
      for (int r = 0; r < 4; ++r) {
        int tok = w*16 + quad*4 + r;
        if (tok < 59 && lm < 8) ao[tok*12 + lm] = acc[r];
      }
    }
    __syncthreads();

    for (int idx = tid; idx < 472; idx += 256) {
      int s = idx >> 3, i = idx & 7;
      const float* wr = ow + (L*8 + i)*8;
      float a = ob[L*8 + i];
      #pragma unroll
      for (int c = 0; c < 8; ++c) a += ao[s*12 + c] * wr[c];
      xr[s*12 + i] = xs[s*12 + i] + a;
    }
    __syncthreads();

    if (tid < 59) {
      float m = 0.f;
      #pragma unroll
      for (int k = 0; k < 8; ++k) m += xr[tid*12 + k];
      m *= 0.125f;
      float v = 0.f;
      #pragma unroll
      for (int k = 0; k < 8; ++k) { float d = xr[tid*12 + k] - m; v += d*d; }
      v *= 0.125f;
      mu[tid] = m; rsd[tid] = rsqrtf(v + 1e-5f);
    }
    __syncthreads();
    for (int idx = tid; idx < 472; idx += 256) {
      int s = idx >> 3, i = idx & 7;
      xs[s*12 + i] = (xr[s*12 + i] - mu[s]) * rsd[s] * g1w[L*8+i] + b1w[L*8+i];
    }
    __syncthreads();

    // ---- FFN via MFMA ----
    mbf8 xf[4];
    #pragma unroll
    for (int tt = 0; tt < 4; ++tt) {
      xf[tt] = zero8();
      if (quad == 0) {
        int tok = tt*16 + lm; if (tok > 58) tok = 58;
        xf[tt] = ld_frag_f32(xs + tok*12);
      }
    }
    mf4 of[4];
    #pragma unroll
    for (int mt = 0; mt < 4; ++mt) { mf4 z = {0.f,0.f,0.f,0.f}; of[mt] = z; }
    const __bf16* w1L = w1B + (size_t)L*128*512;
    const __bf16* w2L = w2B + (size_t)L*64*512;
    const float* f1bL = f1b + L*2048;
    for (int ci = 0; ci < 16; ++ci) {
      #pragma unroll
      for (int u = 0; u < 2; ++u) {
        int ut = ci*8 + w*2 + u;
        mbf8 wa = *(const mbf8*)(w1L + (ut*64 + lane)*8);
        float4 bia = *(const float4*)(f1bL + ut*16 + quad*4);
        int colb = (ut & 7)*16 + quad*4;
        #pragma unroll
        for (int tt = 0; tt < 4; ++tt) {
          mf4 z = {0.f,0.f,0.f,0.f};
          mf4 c = mfma16(wa, xf[tt], z);
          Pk p;
          p.h[0]=(__bf16)fmaxf(c[0]+bia.x,0.f); p.h[1]=(__bf16)fmaxf(c[1]+bia.y,0.f);
          p.h[2]=(__bf16)fmaxf(c[2]+bia.z,0.f); p.h[3]=(__bf16)fmaxf(c[3]+bia.w,0.f);
          *(uint2*)(hbuf + (tt*16 + lm)*140 + colb) = p.u2;
        }
      }
      {
        mbf8 wb = *(const mbf8*)(w2L + ((ci*4 + w)*64 + lane)*8);
        #pragma unroll
        for (int mt = 0; mt < 4; ++mt) {
          mbf8 ah = *(const mbf8*)(hbuf + (mt*16 + lm)*140 + w*32 + quad*8);
          of[mt] = mfma16(ah, wb, of[mt]);
        }
      }
    }
    __syncthreads();
    #pragma unroll
    for (int mt = 0; mt < 4; ++mt)
      #pragma unroll
      for (int r = 0; r < 4; ++r)
        red[((w*4+mt)*16 + quad*4 + r)*17 + lm] = of[mt][r];
    __syncthreads();
    for (int idx = tid; idx < 472; idx += 256) {
      int t = idx >> 3, i = idx & 7, mt = t >> 4, tl = t & 15;
      float s = red[((0*4+mt)*16+tl)*17+i] + red[((1*4+mt)*16+tl)*17+i]
              + red[((2*4+mt)*16+tl)*17+i] + red[((3*4+mt)*16+tl)*17+i];
      xr[t*12 + i] = xs[t*12 + i] + s + f2b[L*8 + i];
    }
    __syncthreads();
    if (tid < 59) {
      float m = 0.f;
      #pragma unroll
      for (int k = 0; k < 8; ++k) m += xr[tid*12 + k];
      m *= 0.125f;
      float v = 0.f;
      #pragma unroll
      for (int k = 0; k < 8; ++k) { float d = xr[tid*12 + k] - m; v += d*d; }
      v *= 0.125f;
      mu[tid] = m; rsd[tid] = rsqrtf(v + 1e-5f);
    }
    __syncthreads();
    for (int idx = tid; idx < 472; idx += 256) {
      int s = idx >> 3, i = idx & 7;
      xs[s*12 + i] = (xr[s*12 + i] - mu[s]) * rsd[s] * g2w[L*8+i] + b2w[L*8+i];
    }
    __syncthreads();
  }

  for (int s = tid; s < 59; s += 256) {
    float a = ymb[0];
    #pragma unroll
    for (int k = 0; k < 8; ++k) a += xs[s*12 + k] * ymw[k];
    outp[(size_t)b*59 + s] = a;
  }
}

// ---------------- Merged encoder kernel: even blocks -> b1, odd -> b2 ----------------
__global__ __launch_bounds__(256) void enc_kernel(
    const float* __restrict__ inp1, const float* __restrict__ inp2,
    const float* __restrict__ xb1,
    const float* __restrict__ qw1, const float* __restrict__ qb1,
    const float* __restrict__ ow1, const float* __restrict__ ob1,
    const float* __restrict__ f1b1, const float* __restrict__ f2b1,
    const float* __restrict__ g1w1, const float* __restrict__ b1w1,
    const float* __restrict__ g2w1, const float* __restrict__ b2w1,
    const float* __restrict__ ymw1, const float* __restrict__ ymb1,
    const __bf16* __restrict__ xw1B, const __bf16* __restrict__ w1B1,
    const __bf16* __restrict__ w2B1,
    const float* __restrict__ xb2,
    const float* __restrict__ qw2, const float* __restrict__ qb2,
    const float* __restrict__ ow2, const float* __restrict__ ob2,
    const float* __restrict__ f1b2, const float* __restrict__ f2b2,
    const float* __restrict__ g1w2, const float* __restrict__ b1w2,
    const float* __restrict__ g2w2, const float* __restrict__ b2w2,
    const float* __restrict__ ymw2, const float* __restrict__ ymb2,
    const __bf16* __restrict__ xw2B, const __bf16* __restrict__ w1B2,
    const __bf16* __restrict__ w2B2,
    float* __restrict__ as_att, float* __restrict__ mrna)
{
  __shared__ __align__(16) float smem[7600];
  int bid = blockIdx.x;
  int b = bid >> 1;
  if ((bid & 1) == 0) {
    run_b1(b, smem, inp1, xb1, qw1, qb1, ow1, ob1, f1b1, f2b1,
           g1w1, b1w1, g2w1, b2w1, ymw1, ymb1, xw1B, w1B1, w2B1, as_att);
  } else {
    run_b2(b, smem, inp2, xb2, qw2, qb2, ow2, ob2, f1b2, f2b2,
           g1w2, b1w2, g2w2, b2w2, ymw2, ymb2, xw2B, w1B2, w2B2, mrna);
  }
}

// ---------------- Final MLP head: 64 blocks x 16 samples, MFMA ----------------
__global__ __launch_bounds__(256) void mlp_kernel(
    const float* __restrict__ as_att, const float* __restrict__ mrna,
    const float* __restrict__ f_gibbs, const float* __restrict__ f_pssm,
    const float* __restrict__ f_gcs, const float* __restrict__ f_ssp,
    const float* __restrict__ f_sse, const float* __restrict__ f_tri,
    const float* __restrict__ f_di, const float* __restrict__ f_sgl,
    const float* __restrict__ f_gc,
    const float* __restrict__ bn_g, const float* __restrict__ bn_b,
    const float* __restrict__ d1b, const float* __restrict__ d2b,
    const float* __restrict__ d3b,
    const float* __restrict__ d4w, const float* __restrict__ d4b,
    const __bf16* __restrict__ d1B, const __bf16* __restrict__ d2B,
    const __bf16* __restrict__ d3B,
    float* __restrict__ outp)
{
  __shared__ __align__(16) float cat[16*268];
  __shared__ __align__(16) float h1[16*268];
  __shared__ __align__(16) float h2[16*68];
  __shared__ __align__(16) float h3[16*17];
  const int tid = threadIdx.x;
  const int bs  = blockIdx.x * 16;
  const int w = tid >> 6, lane = tid & 63, quad = lane >> 4, lm = lane & 15;
  const float bnscale = rsqrtf(1.0f + 1e-5f);

  for (int g = 0; g < 16; ++g) {
    int smp = bs + g;
    for (int j = tid; j < 253; j += 256) {
      float v;
      if (j < 84)       v = as_att[(size_t)smp*84 + j];
      else if (j < 143) v = mrna[(size_t)smp*59 + (j - 84)];
      else {
        int j2 = j - 143;
        if (j2 < 19)       v = f_gibbs[smp*19 + j2];
        else if (j2 < 20)  v = f_pssm[smp];
        else if (j2 < 21)  v = f_gcs[smp];
        else if (j2 < 23)  v = f_ssp[smp*2 + (j2-21)];
        else if (j2 < 25)  v = f_sse[smp*2 + (j2-23)];
        else if (j2 < 89)  v = f_tri[smp*64 + (j2-25)];
        else if (j2 < 105) v = f_di[smp*16 + (j2-89)];
        else if (j2 < 109) v = f_sgl[smp*4 + (j2-105)];
        else               v = f_gc[smp];
      }
      cat[g*268 + j] = v * bnscale * bn_g[j] + bn_b[j];
    }
  }
  if (tid < 48) { int g = tid / 3; cat[g*268 + 253 + tid % 3] = 0.f; }
  __syncthreads();

  {
    mf4 acc[4];
    #pragma unroll
    for (int q = 0; q < 4; ++q) { mf4 z = {0.f,0.f,0.f,0.f}; acc[q] = z; }
    for (int ks = 0; ks < 8; ++ks) {
      mbf8 af = ld_frag_f32(cat + lm*268 + ks*32 + quad*8);
      #pragma unroll
      for (int nt4 = 0; nt4 < 4; ++nt4) {
        int nt = w*4 + nt4;
        mbf8 bf = *(const mbf8*)(d1B + ((nt*8 + ks)*64 + lane)*8);
        acc[nt4] = mfma16(af, bf, acc[nt4]);
      }
    }
    #pragma unroll
    for (int nt4 = 0; nt4 < 4; ++nt4) {
      int n = (w*4 + nt4)*16 + lm;
      float bb = d1b[n];
      #pragma unroll
      for (int r = 0; r < 4; ++r) {
        float a = acc[nt4][r] + bb;
        h1[(quad*4 + r)*268 + n] = (a > 0.f) ? a : 0.01f * a;
      }
    }
  }
  __syncthreads();

  {
    mf4 acc = {0.f,0.f,0.f,0.f};
    for (int ks = 0; ks < 8; ++ks) {
      mbf8 af = ld_frag_f32(h1 + lm*268 + ks*32 + quad*8);
      mbf8 bf = *(const mbf8*)(d2B + ((w*8 + ks)*64 + lane)*8);
      acc = mfma16(af, bf, acc);
    }
    int n = w*16 + lm;
    float bb = d2b[n];
    #pragma unroll
    for (int r = 0; r < 4; ++r) {
      float a = acc[r] + bb;
      h2[(quad*4 + r)*68 + n] = (a > 0.f) ? a : 0.01f * a;
    }
  }
  __syncthreads();

  if (w == 0) {
    mf4 acc = {0.f,0.f,0.f,0.f};
    #pragma unroll
    for (int ks = 0; ks < 2; ++ks) {
      mbf8 af = ld_frag_f32(h2 + lm*68 + ks*32 + quad*8);
      mbf8 bf = *(const mbf8*)(d3B + (ks*64 + lane)*8);
      acc = mfma16(af, bf, acc);
    }
    float bb = d3b[lm];
    #pragma unroll
    for (int r = 0; r < 4; ++r) {
      float a = acc[r] + bb;
      h3[(quad*4 + r)*17 + lm] = (a > 0.f) ? a : 0.01f * a;
    }
  }
  __syncthreads();

  if (tid < 16) {
    float a = d4b[0];
    #pragma unroll
    for (int j = 0; j < 16; ++j) a += h3[tid*17 + j] * d4w[j];
    outp[bs + tid] = 1.f / (1.f + __expf(-a));
  }
}

extern "C" void kernel_launch(void* const* d_in, const int* in_sizes, int n_in,
                              void* d_out, int out_size, void* d_ws, size_t ws_size,
                              hipStream_t stream) {
  const float* rnafm   = (const float*)d_in[0];
  const float* rnafm_m = (const float*)d_in[1];
  const float* f_gibbs = (const float*)d_in[2];
  const float* f_pssm  = (const float*)d_in[3];
  const float* f_gcs   = (const float*)d_in[4];
  const float* f_ssp   = (const float*)d_in[5];
  const float* f_sse   = (const float*)d_in[6];
  const float* f_tri   = (const float*)d_in[7];
  const float* f_di    = (const float*)d_in[8];
  const float* f_sgl   = (const float*)d_in[9];
  const float* f_gc    = (const float*)d_in[10];
  const float* xmap1_w = (const float*)d_in[11];
  const float* xmap1_b = (const float*)d_in[12];
  const float* e1_qw   = (const float*)d_in[13];
  const float* e1_qb   = (const float*)d_in[14];
  const float* e1_ow   = (const float*)d_in[15];
  const float* e1_ob   = (const float*)d_in[16];
  const float* e1_f1w  = (const float*)d_in[17];
  const float* e1_f1b  = (const float*)d_in[18];
  const float* e1_f2w  = (const float*)d_in[19];
  const float* e1_f2b  = (const float*)d_in[20];
  const float* e1_g1   = (const float*)d_in[21];
  const float* e1_b1   = (const float*)d_in[22];
  const float* e1_g2   = (const float*)d_in[23];
  const float* e1_b2   = (const float*)d_in[24];
  const float* ymap1_w = (const float*)d_in[25];
  const float* ymap1_b = (const float*)d_in[26];
  const float* xmap2_w = (const float*)d_in[27];
  const float* xmap2_b = (const float*)d_in[28];
  const float* e2_qw   = (const float*)d_in[29];
  const float* e2_qb   = (const float*)d_in[30];
  const float* e2_ow   = (const float*)d_in[31];
  const float* e2_ob   = (const float*)d_in[32];
  const float* e2_f1w  = (const float*)d_in[33];
  const float* e2_f1b  = (const float*)d_in[34];
  const float* e2_f2w  = (const float*)d_in[35];
  const float* e2_f2b  = (const float*)d_in[36];
  const float* e2_g1   = (const float*)d_in[37];
  const float* e2_b1   = (const float*)d_in[38];
  const float* e2_g2   = (const float*)d_in[39];
  const float* e2_b2   = (const float*)d_in[40];
  const float* ymap2_w = (const float*)d_in[41];
  const float* ymap2_b = (const float*)d_in[42];
  const float* bn_g    = (const float*)d_in[43];
  const float* bn_b    = (const float*)d_in[44];
  const float* d1w     = (const float*)d_in[45];
  const float* d1b     = (const float*)d_in[46];
  const float* d2w     = (const float*)d_in[47];
  const float* d2b     = (const float*)d_in[48];
  const float* d3w     = (const float*)d_in[49];
  const float* d3b     = (const float*)d_in[50];
  const float* d4w     = (const float*)d_in[51];
  const float* d4b     = (const float*)d_in[52];

  float* as_att = (float*)d_ws;                                  // NB*84 f32
  float* mrna   = (float*)((char*)d_ws + (size_t)NB*84*4);       // NB*59 f32
  __bf16* bfb   = (__bf16*)((char*)d_ws + 585728);               // 693248 bf16
  __bf16* xw1B  = bfb;
  __bf16* w1B1  = bfb + 10240;
  __bf16* w2B1  = bfb + 272384;
  __bf16* xw2B  = bfb + 403456;
  __bf16* w1B2  = bfb + 413696;
  __bf16* w2B2  = bfb + 544768;
  __bf16* d1B   = bfb + 610304;
  __bf16* d2B   = bfb + 675840;
  __bf16* d3B   = bfb + 692224;
  float* outp   = (float*)d_out;

  prep_kernel<<<2708, 256, 0, stream>>>(xmap1_w, e1_f1w, e1_f2w, xmap2_w, e2_f1w, e2_f2w,
                                        d1w, d2w, d3w, bfb);

  enc_kernel<<<2*NB, 256, 0, stream>>>(rnafm, rnafm_m,
      xmap1_b, e1_qw, e1_qb, e1_ow, e1_ob, e1_f1b, e1_f2b,
      e1_g1, e1_b1, e1_g2, e1_b2, ymap1_w, ymap1_b, xw1B, w1B1, w2B1,
      xmap2_b, e2_qw, e2_qb, e2_ow, e2_ob, e2_f1b, e2_f2b,
      e2_g1, e2_b1, e2_g2, e2_b2, ymap2_w, ymap2_b, xw2B, w1B2, w2B2,
      as_att, mrna);

  mlp_kernel<<<64, 256, 0, stream>>>(as_att, mrna,
      f_gibbs, f_pssm, f_gcs, f_ssp, f_sse, f_tri, f_di, f_sgl, f_gc,
      bn_g, bn_b, d1b, d2b, d3b, d4w, d4b, d1B, d2B, d3B, outp);
}

// Round 5
// 516.595 us; speedup vs baseline: 1.1488x; 1.1488x over previous
//
#include <hip/hip_runtime.h>
#include <math.h>

#define NB 1024

typedef __bf16 mbf8 __attribute__((ext_vector_type(8)));
typedef float  mf4  __attribute__((ext_vector_type(4)));

union Pk { __bf16 h[4]; uint2 u2; };

__device__ __forceinline__ mf4 mfma16(mbf8 a, mbf8 b, mf4 c) {
  return __builtin_amdgcn_mfma_f32_16x16x32_bf16(a, b, c, 0, 0, 0);
}

__device__ __forceinline__ mbf8 ld_frag_f32(const float* p) {
  float4 u0 = *(const float4*)p;
  float4 u1 = *(const float4*)(p + 4);
  mbf8 v;
  v[0]=(__bf16)u0.x; v[1]=(__bf16)u0.y; v[2]=(__bf16)u0.z; v[3]=(__bf16)u0.w;
  v[4]=(__bf16)u1.x; v[5]=(__bf16)u1.y; v[6]=(__bf16)u1.z; v[7]=(__bf16)u1.w;
  return v;
}

__device__ __forceinline__ mbf8 ld_frag_f32_scaled(const float* p, float s) {
  float4 u0 = *(const float4*)p;
  float4 u1 = *(const float4*)(p + 4);
  mbf8 v;
  v[0]=(__bf16)(u0.x*s); v[1]=(__bf16)(u0.y*s); v[2]=(__bf16)(u0.z*s); v[3]=(__bf16)(u0.w*s);
  v[4]=(__bf16)(u1.x*s); v[5]=(__bf16)(u1.y*s); v[6]=(__bf16)(u1.z*s); v[7]=(__bf16)(u1.w*s);
  return v;
}

__device__ __forceinline__ mbf8 zero8() {
  mbf8 v;
  #pragma unroll
  for (int q = 0; q < 8; ++q) v[q] = (__bf16)0.f;
  return v;
}

// ---------------- prep: fp32 weights -> bf16 MFMA fragments in ws ----------------
__global__ __launch_bounds__(256) void prep_kernel(
    const float* __restrict__ xw1, const float* __restrict__ f1w1, const float* __restrict__ f2w1,
    const float* __restrict__ xw2, const float* __restrict__ f1w2, const float* __restrict__ f2w2,
    const float* __restrict__ d1w, const float* __restrict__ d2w, const float* __restrict__ d3w,
    __bf16* __restrict__ out)
{
  int idx = blockIdx.x * 256 + threadIdx.x;
  if (idx >= 693248) return;
  int which, local;
  if (idx < 10240)       { which = 0; local = idx; }
  else if (idx < 272384) { which = 1; local = idx - 10240; }
  else if (idx < 403456) { which = 2; local = idx - 272384; }
  else if (idx < 413696) { which = 3; local = idx - 403456; }
  else if (idx < 544768) { which = 4; local = idx - 413696; }
  else if (idx < 610304) { which = 5; local = idx - 544768; }
  else if (idx < 675840) { which = 6; local = idx - 610304; }
  else if (idx < 692224) { which = 7; local = idx - 675840; }
  else                   { which = 8; local = idx - 692224; }
  int tile = local >> 9, r = local & 511, lane = r >> 3, j = r & 7;
  int quad = lane >> 4, lm = lane & 15, khi = quad * 8 + j;
  float val = 0.f;
  switch (which) {
    case 0: { int k = tile*32 + khi; val = xw1[lm*640 + k]; } break;
    case 1: { int L = tile >> 7, nt = tile & 127, n = nt*16 + lm;
              val = (khi < 16) ? f1w1[(L*2048 + n)*16 + khi] : 0.f; } break;
    case 2: { int L = tile >> 6, ks = tile & 63, k = ks*32 + khi;
              val = f2w1[(L*16 + lm)*2048 + k]; } break;
    case 3: { int k = tile*32 + khi; val = (lm < 8) ? xw2[lm*640 + k] : 0.f; } break;
    case 4: { int L = tile >> 7, nt = tile & 127, n = nt*16 + lm;
              val = (khi < 8) ? f1w2[(L*2048 + n)*8 + khi] : 0.f; } break;
    case 5: { int L = tile >> 6, ks = tile & 63, k = ks*32 + khi;
              val = (lm < 8) ? f2w2[(L*8 + lm)*2048 + k] : 0.f; } break;
    case 6: { int nt = tile >> 3, ks = tile & 7, k = ks*32 + khi;
              val = (k < 253) ? d1w[(nt*16 + lm)*253 + k] : 0.f; } break;
    case 7: { int nt = tile >> 3, ks = tile & 7, k = ks*32 + khi;
              val = d2w[(nt*16 + lm)*256 + k]; } break;
    default:{ int ks = tile, k = ks*32 + khi;
              val = d3w[lm*64 + k]; } break;
  }
  out[idx] = (__bf16)val;
}

// ---------------- Branch 1 body: siRNA, S=21, D=16, H=2, L=4 ----------------
__device__ __forceinline__ void run_b1(int b, float* smem,
    const float* __restrict__ inp, const float* __restrict__ xb,
    const float* __restrict__ qw, const float* __restrict__ qb,
    const float* __restrict__ ow, const float* __restrict__ ob,
    const float* __restrict__ f1b, const float* __restrict__ f2b,
    const float* __restrict__ g1w, const float* __restrict__ b1w,
    const float* __restrict__ g2w, const float* __restrict__ b2w,
    const float* __restrict__ ymw, const float* __restrict__ ymb,
    const __bf16* __restrict__ xwB, const __bf16* __restrict__ w1B,
    const __bf16* __restrict__ w2B, float* __restrict__ outp)
{
  float* xs   = smem;         // [21][20]
  float* ao   = smem + 420;   // [21][20]
  float* pool = smem + 840;   // 4352 floats

  const int tid = threadIdx.x;
  const int w = tid >> 6, lane = tid & 63, quad = lane >> 4, lm = lane & 15;
  float* qkv = pool;                              // [21][52]
  __bf16* pbuf = (__bf16*)(pool + 1092);          // 4 waves x [16][40] bf16
  __bf16* hbuf = (__bf16*)pool;                   // [32][264] bf16
  float* red = pool;                              // [8][16][17]
  const float* Ain = inp + (size_t)b * 21 * 640;

  // ---- input projection via MFMA ----
  mf4 pc0 = {0.f,0.f,0.f,0.f}, pc1 = {0.f,0.f,0.f,0.f};
  for (int i = 0; i < 5; ++i) {
    int ks = w*5 + i;
    mbf8 bv = *(const mbf8*)(xwB + (ks*64 + lane)*8);
    #pragma unroll
    for (int mt = 0; mt < 2; ++mt) {
      int row = mt*16 + lm; row = row > 20 ? 20 : row;
      mbf8 av = ld_frag_f32(Ain + row*640 + ks*32 + quad*8);
      if (mt == 0) pc0 = mfma16(av, bv, pc0); else pc1 = mfma16(av, bv, pc1);
    }
  }
  #pragma unroll
  for (int r = 0; r < 4; ++r) {
    red[((w*2+0)*16 + quad*4 + r)*17 + lm] = pc0[r];
    red[((w*2+1)*16 + quad*4 + r)*17 + lm] = pc1[r];
  }
  __syncthreads();
  {
    const float lf = -logf(10000.0f) / 16.0f;
    for (int idx = tid; idx < 336; idx += 256) {
      int t = idx >> 4, i = idx & 15, mt = t >> 4, tl = t & 15;
      float s = red[((0+mt)*16+tl)*17+i] + red[((2+mt)*16+tl)*17+i]
              + red[((4+mt)*16+tl)*17+i] + red[((6+mt)*16+tl)*17+i];
      float freq = expf((float)((i>>1)*2) * lf);
      float pe = (i & 1) ? cosf((float)t * freq) : sinf((float)t * freq);
      xs[t*20 + i] = s + xb[i] + pe;
    }
  }
  __syncthreads();

  for (int L = 0; L < 4; ++L) {
    // qkv = x @ qkv_w^T + b -> [21][48]
    for (int idx = tid; idx < 1008; idx += 256) {
      int s = idx / 48, e = idx % 48;
      const float* wr = qw + (L*48 + e)*16;
      float a = qb[L*48 + e];
      #pragma unroll
      for (int k = 0; k < 16; ++k) a += xs[s*20+k] * wr[k];
      qkv[s*52 + e] = a;
    }
    __syncthreads();

    { // ---- wave-local fused attention: wave w -> (h=w>>1, mt=w&1) ----
      int h = w >> 1, mt = w & 1;
      __bf16* pb = pbuf + w*640;   // [16][40]
      int tokq = mt*16 + lm; tokq = tokq > 20 ? 20 : tokq;
      mbf8 qf = zero8();
      if (quad == 0) qf = ld_frag_f32_scaled(qkv + tokq*52 + h*8, 0.35355339059327373f);
      float scr[2][4];
      #pragma unroll
      for (int nt = 0; nt < 2; ++nt) {
        int key = nt*16 + lm; key = key > 20 ? 20 : key;
        mbf8 kf = zero8();
        if (quad == 0) kf = ld_frag_f32(qkv + key*52 + 16 + h*8);
        mf4 z = {0.f,0.f,0.f,0.f};
        mf4 c = mfma16(qf, kf, z);
        int col = nt*16 + lm;
        #pragma unroll
        for (int r = 0; r < 4; ++r) scr[nt][r] = (col < 21) ? c[r] : -1e30f;
      }
      // in-register softmax per row (rows r, cols over nt x lm)
      #pragma unroll
      for (int r = 0; r < 4; ++r) {
        float m = fmaxf(scr[0][r], scr[1][r]);
        m = fmaxf(m, __shfl_xor(m, 1)); m = fmaxf(m, __shfl_xor(m, 2));
        m = fmaxf(m, __shfl_xor(m, 4)); m = fmaxf(m, __shfl_xor(m, 8));
        float e0 = __expf(scr[0][r] - m), e1 = __expf(scr[1][r] - m);
        float s = e0 + e1;
        s += __shfl_xor(s, 1); s += __shfl_xor(s, 2);
        s += __shfl_xor(s, 4); s += __shfl_xor(s, 8);
        float inv = 1.f / s;
        scr[0][r] = e0 * inv; scr[1][r] = e1 * inv;
      }
      // transpose P through wave-private LDS (per-wave DS ops are in-order)
      #pragma unroll
      for (int nt = 0; nt < 2; ++nt)
        #pragma unroll
        for (int r = 0; r < 4; ++r)
          pb[(quad*4 + r)*40 + nt*16 + lm] = (__bf16)scr[nt][r];
      mbf8 pf = *(const mbf8*)(pb + lm*40 + quad*8);
      mbf8 vf = zero8();
      #pragma unroll
      for (int j = 0; j < 8; ++j) {
        int k = quad*8 + j;
        vf[j] = (__bf16)((lm < 8 && k < 21) ? qkv[k*52 + 32 + h*8 + lm] : 0.f);
      }
      mf4 z = {0.f,0.f,0.f,0.f};
      mf4 c = mfma16(pf, vf, z);
      #pragma unroll
      for (int r = 0; r < 4; ++r) {
        int tok = mt*16 + quad*4 + r;
        if (tok < 21 && lm < 8) ao[tok*20 + h*8 + lm] = c[r];
      }
    }
    __syncthreads();

    // ---- outproj + residual + LN1 fused (16-thread row groups) ----
    for (int idx = tid; idx < 336; idx += 256) {
      int s = idx >> 4, i = idx & 15;
      const float* wr = ow + (L*16 + i)*16;
      float a = ob[L*16 + i];
      #pragma unroll
      for (int c = 0; c < 16; ++c) a += ao[s*20 + c] * wr[c];
      float v = xs[s*20 + i] + a;
      float m = v;
      m += __shfl_xor(m, 1); m += __shfl_xor(m, 2);
      m += __shfl_xor(m, 4); m += __shfl_xor(m, 8);
      m *= (1.f/16.f);
      float d = v - m;
      float va = d*d;
      va += __shfl_xor(va, 1); va += __shfl_xor(va, 2);
      va += __shfl_xor(va, 4); va += __shfl_xor(va, 8);
      va *= (1.f/16.f);
      xs[s*20 + i] = d * rsqrtf(va + 1e-5f) * g1w[L*16+i] + b1w[L*16+i];
    }
    __syncthreads();

    // ---- FFN via MFMA (barrier-free inner loop) ----
    mbf8 xf0 = zero8(), xf1 = zero8();
    if (quad < 2) {
      int t0 = lm;
      int t1 = 16 + lm; if (t1 > 20) t1 = 20;
      xf0 = ld_frag_f32(xs + t0*20 + quad*8);
      xf1 = ld_frag_f32(xs + t1*20 + quad*8);
    }
    mf4 of0 = {0.f,0.f,0.f,0.f}, of1 = {0.f,0.f,0.f,0.f};
    const __bf16* w1L = w1B + (size_t)L*128*512;
    const __bf16* w2L = w2B + (size_t)L*64*512;
    const float* f1bL = f1b + L*2048;
    for (int ci = 0; ci < 8; ++ci) {
      #pragma unroll
      for (int u = 0; u < 4; ++u) {
        int ut = ci*16 + w*4 + u;
        mbf8 wa = *(const mbf8*)(w1L + (ut*64 + lane)*8);
        float4 bia = *(const float4*)(f1bL + ut*16 + quad*4);
        mf4 z = {0.f,0.f,0.f,0.f};
        mf4 c0 = mfma16(wa, xf0, z);
        mf4 c1 = mfma16(wa, xf1, z);
        Pk p0, p1;
        p0.h[0]=(__bf16)fmaxf(c0[0]+bia.x,0.f); p0.h[1]=(__bf16)fmaxf(c0[1]+bia.y,0.f);
        p0.h[2]=(__bf16)fmaxf(c0[2]+bia.z,0.f); p0.h[3]=(__bf16)fmaxf(c0[3]+bia.w,0.f);
        p1.h[0]=(__bf16)fmaxf(c1[0]+bia.x,0.f); p1.h[1]=(__bf16)fmaxf(c1[1]+bia.y,0.f);
        p1.h[2]=(__bf16)fmaxf(c1[2]+bia.z,0.f); p1.h[3]=(__bf16)fmaxf(c1[3]+bia.w,0.f);
        int colb = (ut & 15)*16 + quad*4;
        *(uint2*)(hbuf + lm*264 + colb)        = p0.u2;
        *(uint2*)(hbuf + (16 + lm)*264 + colb) = p1.u2;
      }
      #pragma unroll
      for (int kk = 0; kk < 2; ++kk) {
        int ksl = w*2 + kk;
        mbf8 wb = *(const mbf8*)(w2L + ((ci*8 + ksl)*64 + lane)*8);
        mbf8 a0 = *(const mbf8*)(hbuf + lm*264 + ksl*32 + quad*8);
        mbf8 a1 = *(const mbf8*)(hbuf + (16 + lm)*264 + ksl*32 + quad*8);
        of0 = mfma16(a0, wb, of0);
        of1 = mfma16(a1, wb, of1);
      }
    }
    __syncthreads();   // hbuf dead; red reuse
    #pragma unroll
    for (int r = 0; r < 4; ++r) {
      red[((w*2+0)*16 + quad*4 + r)*17 + lm] = of0[r];
      red[((w*2+1)*16 + quad*4 + r)*17 + lm] = of1[r];
    }
    __syncthreads();
    // ---- FFN reduce + residual + LN2 fused ----
    for (int idx = tid; idx < 336; idx += 256) {
      int t = idx >> 4, i = idx & 15, mt = t >> 4, tl = t & 15;
      float s = red[((0+mt)*16+tl)*17+i] + red[((2+mt)*16+tl)*17+i]
              + red[((4+mt)*16+tl)*17+i] + red[((6+mt)*16+tl)*17+i];
      float v = xs[t*20 + i] + s + f2b[L*16 + i];
      float m = v;
      m += __shfl_xor(m, 1); m += __shfl_xor(m, 2);
      m += __shfl_xor(m, 4); m += __shfl_xor(m, 8);
      m *= (1.f/16.f);
      float d = v - m;
      float va = d*d;
      va += __shfl_xor(va, 1); va += __shfl_xor(va, 2);
      va += __shfl_xor(va, 4); va += __shfl_xor(va, 8);
      va *= (1.f/16.f);
      xs[t*20 + i] = d * rsqrtf(va + 1e-5f) * g2w[L*16+i] + b2w[L*16+i];
    }
    __syncthreads();
  }

  for (int idx = tid; idx < 84; idx += 256) {
    int s = idx >> 2, j = idx & 3;
    float a = ymb[j];
    #pragma unroll
    for (int k = 0; k < 16; ++k) a += xs[s*20 + k] * ymw[j*16 + k];
    outp[(size_t)b*84 + idx] = a;
  }
}

// ---------------- Branch 2 body: mRNA, S=59, D=8, H=1, L=2 ----------------
__device__ __forceinline__ void run_b2(int b, float* smem,
    const float* __restrict__ inp, const float* __restrict__ xb,
    const float* __restrict__ qw, const float* __restrict__ qb,
    const float* __restrict__ ow, const float* __restrict__ ob,
    const float* __restrict__ f1b, const float* __restrict__ f2b,
    const float* __restrict__ g1w, const float* __restrict__ b1w,
    const float* __restrict__ g2w, const float* __restrict__ b2w,
    const float* __restrict__ ymw, const float* __restrict__ ymb,
    const __bf16* __restrict__ xwB, const __bf16* __restrict__ w1B,
    const __bf16* __restrict__ w2B, float* __restrict__ outp)
{
  float* xs   = smem;         // [59][12]
  float* ao   = smem + 708;   // [59][12]
  float* pool = smem + 1416;  // 4352 floats

  const int tid = threadIdx.x;
  const int w = tid >> 6, lane = tid & 63, quad = lane >> 4, lm = lane & 15;
  float* qkv = pool;                              // [59][28]
  __bf16* pbuf = (__bf16*)(pool + 1652);          // 4 waves x [16][72] bf16
  __bf16* hbuf = (__bf16*)pool;                   // [64][136] bf16
  float* red = pool;                              // [16][16][17]
  const float* Ain = inp + (size_t)b * 59 * 640;

  mf4 pc[4];
  #pragma unroll
  for (int mt = 0; mt < 4; ++mt) { mf4 z = {0.f,0.f,0.f,0.f}; pc[mt] = z; }
  for (int i = 0; i < 5; ++i) {
    int ks = w*5 + i;
    mbf8 bv = *(const mbf8*)(xwB + (ks*64 + lane)*8);
    #pragma unroll
    for (int mt = 0; mt < 4; ++mt) {
      int row = mt*16 + lm; row = row > 58 ? 58 : row;
      mbf8 av = ld_frag_f32(Ain + row*640 + ks*32 + quad*8);
      pc[mt] = mfma16(av, bv, pc[mt]);
    }
  }
  #pragma unroll
  for (int mt = 0; mt < 4; ++mt)
    #pragma unroll
    for (int r = 0; r < 4; ++r)
      red[((w*4+mt)*16 + quad*4 + r)*17 + lm] = pc[mt][r];
  __syncthreads();
  {
    const float lf = -logf(10000.0f) / 8.0f;
    for (int idx = tid; idx < 472; idx += 256) {
      int t = idx >> 3, i = idx & 7, mt = t >> 4, tl = t & 15;
      float s = red[((0*4+mt)*16+tl)*17+i] + red[((1*4+mt)*16+tl)*17+i]
              + red[((2*4+mt)*16+tl)*17+i] + red[((3*4+mt)*16+tl)*17+i];
      float freq = expf((float)((i>>1)*2) * lf);
      float pe = (i & 1) ? cosf((float)t * freq) : sinf((float)t * freq);
      xs[t*12 + i] = s + xb[i] + pe;
    }
  }
  __syncthreads();

  for (int L = 0; L < 2; ++L) {
    for (int idx = tid; idx < 1416; idx += 256) {
      int s = idx / 24, e = idx % 24;
      const float* wr = qw + (L*24 + e)*8;
      float a = qb[L*24 + e];
      #pragma unroll
      for (int k = 0; k < 8; ++k) a += xs[s*12+k] * wr[k];
      qkv[s*28 + e] = a;
    }
    __syncthreads();

    { // ---- wave-local fused attention: wave w = m-tile ----
      __bf16* pb = pbuf + w*1152;   // [16][72]
      int tokq = w*16 + lm; tokq = tokq > 58 ? 58 : tokq;
      mbf8 qf = zero8();
      if (quad == 0) qf = ld_frag_f32_scaled(qkv + tokq*28, 0.35355339059327373f);
      float scr[4][4];
      #pragma unroll
      for (int nt = 0; nt < 4; ++nt) {
        int key = nt*16 + lm; key = key > 58 ? 58 : key;
        mbf8 kf = zero8();
        if (quad == 0) kf = ld_frag_f32(qkv + key*28 + 8);
        mf4 z = {0.f,0.f,0.f,0.f};
        mf4 c = mfma16(qf, kf, z);
        int col = nt*16 + lm;
        #pragma unroll
        for (int r = 0; r < 4; ++r) scr[nt][r] = (col < 59) ? c[r] : -1e30f;
      }
      #pragma unroll
      for (int r = 0; r < 4; ++r) {
        float m = fmaxf(fmaxf(scr[0][r], scr[1][r]), fmaxf(scr[2][r], scr[3][r]));
        m = fmaxf(m, __shfl_xor(m, 1)); m = fmaxf(m, __shfl_xor(m, 2));
        m = fmaxf(m, __shfl_xor(m, 4)); m = fmaxf(m, __shfl_xor(m, 8));
        float e0 = __expf(scr[0][r] - m), e1 = __expf(scr[1][r] - m);
        float e2 = __expf(scr[2][r] - m), e3 = __expf(scr[3][r] - m);
        float s = (e0 + e1) + (e2 + e3);
        s += __shfl_xor(s, 1); s += __shfl_xor(s, 2);
        s += __shfl_xor(s, 4); s += __shfl_xor(s, 8);
        float inv = 1.f / s;
        scr[0][r] = e0 * inv; scr[1][r] = e1 * inv;
        scr[2][r] = e2 * inv; scr[3][r] = e3 * inv;
      }
      #pragma unroll
      for (int nt = 0; nt < 4; ++nt)
        #pragma unroll
        for (int r = 0; r < 4; ++r)
          pb[(quad*4 + r)*72 + nt*16 + lm] = (__bf16)scr[nt][r];
      mf4 acc = {0.f,0.f,0.f,0.f};
      #pragma unroll
      for (int kk = 0; kk < 2; ++kk) {
        mbf8 pf = *(const mbf8*)(pb + lm*72 + kk*32 + quad*8);
        mbf8 vf = zero8();
        #pragma unroll
        for (int j = 0; j < 8; ++j) {
          int k = kk*32 + quad*8 + j;
          vf[j] = (__bf16)((lm < 8 && k < 59) ? qkv[k*28 + 16 + lm] : 0.f);
        }
        acc = mfma16(pf, vf, acc);
      }
      #pragma unroll
      for (int r = 0; r < 4; ++r) {
        int tok = w*16 + quad*4 + r;
        if (tok < 59 && lm < 8) ao[tok*12 + lm] = acc[r];
      }
    }
    __syncthreads();

    // ---- outproj + residual + LN1 fused (8-thread row groups) ----
    for (int idx = tid; idx < 472; idx += 256) {
      int s = idx >> 3, i = idx & 7;
      const float* wr = ow + (L*8 + i)*8;
      float a = ob[L*8 + i];
      #pragma unroll
      for (int c = 0; c < 8; ++c) a += ao[s*12 + c] * wr[c];
      float v = xs[s*12 + i] + a;
      float m = v;
      m += __shfl_xor(m, 1); m += __shfl_xor(m, 2); m += __shfl_xor(m, 4);
      m *= 0.125f;
      float d = v - m;
      float va = d*d;
      va += __shfl_xor(va, 1); va += __shfl_xor(va, 2); va += __shfl_xor(va, 4);
      va *= 0.125f;
      xs[s*12 + i] = d * rsqrtf(va + 1e-5f) * g1w[L*8+i] + b1w[L*8+i];
    }
    __syncthreads();

    // ---- FFN via MFMA ----
    mbf8 xf[4];
    #pragma unroll
    for (int tt = 0; tt < 4; ++tt) {
      xf[tt] = zero8();
      if (quad == 0) {
        int tok = tt*16 + lm; if (tok > 58) tok = 58;
        xf[tt] = ld_frag_f32(xs + tok*12);
      }
    }
    mf4 of[4];
    #pragma unroll
    for (int mt = 0; mt < 4; ++mt) { mf4 z = {0.f,0.f,0.f,0.f}; of[mt] = z; }
    const __bf16* w1L = w1B + (size_t)L*128*512;
    const __bf16* w2L = w2B + (size_t)L*64*512;
    const float* f1bL = f1b + L*2048;
    for (int ci = 0; ci < 16; ++ci) {
      #pragma unroll
      for (int u = 0; u < 2; ++u) {
        int ut = ci*8 + w*2 + u;
        mbf8 wa = *(const mbf8*)(w1L + (ut*64 + lane)*8);
        float4 bia = *(const float4*)(f1bL + ut*16 + quad*4);
        int colb = (ut & 7)*16 + quad*4;
        #pragma unroll
        for (int tt = 0; tt < 4; ++tt) {
          mf4 z = {0.f,0.f,0.f,0.f};
          mf4 c = mfma16(wa, xf[tt], z);
          Pk p;
          p.h[0]=(__bf16)fmaxf(c[0]+bia.x,0.f); p.h[1]=(__bf16)fmaxf(c[1]+bia.y,0.f);
          p.h[2]=(__bf16)fmaxf(c[2]+bia.z,0.f); p.h[3]=(__bf16)fmaxf(c[3]+bia.w,0.f);
          *(uint2*)(hbuf + (tt*16 + lm)*136 + colb) = p.u2;
        }
      }
      {
        mbf8 wb = *(const mbf8*)(w2L + ((ci*4 + w)*64 + lane)*8);
        #pragma unroll
        for (int mt = 0; mt < 4; ++mt) {
          mbf8 ah = *(const mbf8*)(hbuf + (mt*16 + lm)*136 + w*32 + quad*8);
          of[mt] = mfma16(ah, wb, of[mt]);
        }
      }
    }
    __syncthreads();
    #pragma unroll
    for (int mt = 0; mt < 4; ++mt)
      #pragma unroll
      for (int r = 0; r < 4; ++r)
        red[((w*4+mt)*16 + quad*4 + r)*17 + lm] = of[mt][r];
    __syncthreads();
    // ---- FFN reduce + residual + LN2 fused ----
    for (int idx = tid; idx < 472; idx += 256) {
      int t = idx >> 3, i = idx & 7, mt = t >> 4, tl = t & 15;
      float s = red[((0*4+mt)*16+tl)*17+i] + red[((1*4+mt)*16+tl)*17+i]
              + red[((2*4+mt)*16+tl)*17+i] + red[((3*4+mt)*16+tl)*17+i];
      float v = xs[t*12 + i] + s + f2b[L*8 + i];
      float m = v;
      m += __shfl_xor(m, 1); m += __shfl_xor(m, 2); m += __shfl_xor(m, 4);
      m *= 0.125f;
      float d = v - m;
      float va = d*d;
      va += __shfl_xor(va, 1); va += __shfl_xor(va, 2); va += __shfl_xor(va, 4);
      va *= 0.125f;
      xs[t*12 + i] = d * rsqrtf(va + 1e-5f) * g2w[L*8+i] + b2w[L*8+i];
    }
    __syncthreads();
  }

  for (int s = tid; s < 59; s += 256) {
    float a = ymb[0];
    #pragma unroll
    for (int k = 0; k < 8; ++k) a += xs[s*12 + k] * ymw[k];
    outp[(size_t)b*59 + s] = a;
  }
}

// ---------------- Merged encoder kernel: even blocks -> b1, odd -> b2 ----------------
__global__ __launch_bounds__(256) void enc_kernel(
    const float* __restrict__ inp1, const float* __restrict__ inp2,
    const float* __restrict__ xb1,
    const float* __restrict__ qw1, const float* __restrict__ qb1,
    const float* __restrict__ ow1, const float* __restrict__ ob1,
    const float* __restrict__ f1b1, const float* __restrict__ f2b1,
    const float* __restrict__ g1w1, const float* __restrict__ b1w1,
    const float* __restrict__ g2w1, const float* __restrict__ b2w1,
    const float* __restrict__ ymw1, const float* __restrict__ ymb1,
    const __bf16* __restrict__ xw1B, const __bf16* __restrict__ w1B1,
    const __bf16* __restrict__ w2B1,
    const float* __restrict__ xb2,
    const float* __restrict__ qw2, const float* __restrict__ qb2,
    const float* __restrict__ ow2, const float* __restrict__ ob2,
    const float* __restrict__ f1b2, const float* __restrict__ f2b2,
    const float* __restrict__ g1w2, const float* __restrict__ b1w2,
    const float* __restrict__ g2w2, const float* __restrict__ b2w2,
    const float* __restrict__ ymw2, const float* __restrict__ ymb2,
    const __bf16* __restrict__ xw2B, const __bf16* __restrict__ w1B2,
    const __bf16* __restrict__ w2B2,
    float* __restrict__ as_att, float* __restrict__ mrna)
{
  __shared__ __align__(16) float smem[5792];
  int bid = blockIdx.x;
  int b = bid >> 1;
  if ((bid & 1) == 0) {
    run_b1(b, smem, inp1, xb1, qw1, qb1, ow1, ob1, f1b1, f2b1,
           g1w1, b1w1, g2w1, b2w1, ymw1, ymb1, xw1B, w1B1, w2B1, as_att);
  } else {
    run_b2(b, smem, inp2, xb2, qw2, qb2, ow2, ob2, f1b2, f2b2,
           g1w2, b1w2, g2w2, b2w2, ymw2, ymb2, xw2B, w1B2, w2B2, mrna);
  }
}

// ---------------- Final MLP head: 64 blocks x 16 samples, MFMA ----------------
__global__ __launch_bounds__(256) void mlp_kernel(
    const float* __restrict__ as_att, const float* __restrict__ mrna,
    const float* __restrict__ f_gibbs, const float* __restrict__ f_pssm,
    const float* __restrict__ f_gcs, const float* __restrict__ f_ssp,
    const float* __restrict__ f_sse, const float* __restrict__ f_tri,
    const float* __restrict__ f_di, const float* __restrict__ f_sgl,
    const float* __restrict__ f_gc,
    const float* __restrict__ bn_g, const float* __restrict__ bn_b,
    const float* __restrict__ d1b, const float* __restrict__ d2b,
    const float* __restrict__ d3b,
    const float* __restrict__ d4w, const float* __restrict__ d4b,
    const __bf16* __restrict__ d1B, const __bf16* __restrict__ d2B,
    const __bf16* __restrict__ d3B,
    float* __restrict__ outp)
{
  __shared__ __align__(16) float cat[16*268];
  __shared__ __align__(16) float h1[16*268];
  __shared__ __align__(16) float h2[16*68];
  __shared__ __align__(16) float h3[16*17];
  const int tid = threadIdx.x;
  const int bs  = blockIdx.x * 16;
  const int w = tid >> 6, lane = tid & 63, quad = lane >> 4, lm = lane & 15;
  const float bnscale = rsqrtf(1.0f + 1e-5f);

  for (int g = 0; g < 16; ++g) {
    int smp = bs + g;
    for (int j = tid; j < 253; j += 256) {
      float v;
      if (j < 84)       v = as_att[(size_t)smp*84 + j];
      else if (j < 143) v = mrna[(size_t)smp*59 + (j - 84)];
      else {
        int j2 = j - 143;
        if (j2 < 19)       v = f_gibbs[smp*19 + j2];
        else if (j2 < 20)  v = f_pssm[smp];
        else if (j2 < 21)  v = f_gcs[smp];
        else if (j2 < 23)  v = f_ssp[smp*2 + (j2-21)];
        else if (j2 < 25)  v = f_sse[smp*2 + (j2-23)];
        else if (j2 < 89)  v = f_tri[smp*64 + (j2-25)];
        else if (j2 < 105) v = f_di[smp*16 + (j2-89)];
        else if (j2 < 109) v = f_sgl[smp*4 + (j2-105)];
        else               v = f_gc[smp];
      }
      cat[g*268 + j] = v * bnscale * bn_g[j] + bn_b[j];
    }
  }
  if (tid < 48) { int g = tid / 3; cat[g*268 + 253 + tid % 3] = 0.f; }
  __syncthreads();

  {
    mf4 acc[4];
    #pragma unroll
    for (int q = 0; q < 4; ++q) { mf4 z = {0.f,0.f,0.f,0.f}; acc[q] = z; }
    for (int ks = 0; ks < 8; ++ks) {
      mbf8 af = ld_frag_f32(cat + lm*268 + ks*32 + quad*8);
      #pragma unroll
      for (int nt4 = 0; nt4 < 4; ++nt4) {
        int nt = w*4 + nt4;
        mbf8 bf = *(const mbf8*)(d1B + ((nt*8 + ks)*64 + lane)*8);
        acc[nt4] = mfma16(af, bf, acc[nt4]);
      }
    }
    #pragma unroll
    for (int nt4 = 0; nt4 < 4; ++nt4) {
      int n = (w*4 + nt4)*16 + lm;
      float bb = d1b[n];
      #pragma unroll
      for (int r = 0; r < 4; ++r) {
        float a = acc[nt4][r] + bb;
        h1[(quad*4 + r)*268 + n] = (a > 0.f) ? a : 0.01f * a;
      }
    }
  }
  __syncthreads();

  {
    mf4 acc = {0.f,0.f,0.f,0.f};
    for (int ks = 0; ks < 8; ++ks) {
      mbf8 af = ld_frag_f32(h1 + lm*268 + ks*32 + quad*8);
      mbf8 bf = *(const mbf8*)(d2B + ((w*8 + ks)*64 + lane)*8);
      acc = mfma16(af, bf, acc);
    }
    int n = w*16 + lm;
    float bb = d2b[n];
    #pragma unroll
    for (int r = 0; r < 4; ++r) {
      float a = acc[r] + bb;
      h2[(quad*4 + r)*68 + n] = (a > 0.f) ? a : 0.01f * a;
    }
  }
  __syncthreads();

  if (w == 0) {
    mf4 acc = {0.f,0.f,0.f,0.f};
    #pragma unroll
    for (int ks = 0; ks < 2; ++ks) {
      mbf8 af = ld_frag_f32(h2 + lm*68 + ks*32 + quad*8);
      mbf8 bf = *(const mbf8*)(d3B + (ks*64 + lane)*8);
      acc = mfma16(af, bf, acc);
    }
    float bb = d3b[lm];
    #pragma unroll
    for (int r = 0; r < 4; ++r) {
      float a = acc[r] + bb;
      h3[(quad*4 + r)*17 + lm] = (a > 0.f) ? a : 0.01f * a;
    }
  }
  __syncthreads();

  if (tid < 16) {
    float a = d4b[0];
    #pragma unroll
    for (int j = 0; j < 16; ++j) a += h3[tid*17 + j] * d4w[j];
    outp[bs + tid] = 1.f / (1.f + __expf(-a));
  }
}

extern "C" void kernel_launch(void* const* d_in, const int* in_sizes, int n_in,
                              void* d_out, int out_size, void* d_ws, size_t ws_size,
                              hipStream_t stream) {
  const float* rnafm   = (const float*)d_in[0];
  const float* rnafm_m = (const float*)d_in[1];
  const float* f_gibbs = (const float*)d_in[2];
  const float* f_pssm  = (const float*)d_in[3];
  const float* f_gcs   = (const float*)d_in[4];
  const float* f_ssp   = (const float*)d_in[5];
  const float* f_sse   = (const float*)d_in[6];
  const float* f_tri   = (const float*)d_in[7];
  const float* f_di    = (const float*)d_in[8];
  const float* f_sgl   = (const float*)d_in[9];
  const float* f_gc    = (const float*)d_in[10];
  const float* xmap1_w = (const float*)d_in[11];
  const float* xmap1_b = (const float*)d_in[12];
  const float* e1_qw   = (const float*)d_in[13];
  const float* e1_qb   = (const float*)d_in[14];
  const float* e1_ow   = (const float*)d_in[15];
  const float* e1_ob   = (const float*)d_in[16];
  const float* e1_f1w  = (const float*)d_in[17];
  const float* e1_f1b  = (const float*)d_in[18];
  const float* e1_f2w  = (const float*)d_in[19];
  const float* e1_f2b  = (const float*)d_in[20];
  const float* e1_g1   = (const float*)d_in[21];
  const float* e1_b1   = (const float*)d_in[22];
  const float* e1_g2   = (const float*)d_in[23];
  const float* e1_b2   = (const float*)d_in[24];
  const float* ymap1_w = (const float*)d_in[25];
  const float* ymap1_b = (const float*)d_in[26];
  const float* xmap2_w = (const float*)d_in[27];
  const float* xmap2_b = (const float*)d_in[28];
  const float* e2_qw   = (const float*)d_in[29];
  const float* e2_qb   = (const float*)d_in[30];
  const float* e2_ow   = (const float*)d_in[31];
  const float* e2_ob   = (const float*)d_in[32];
  const float* e2_f1w  = (const float*)d_in[33];
  const float* e2_f1b  = (const float*)d_in[34];
  const float* e2_f2w  = (const float*)d_in[35];
  const float* e2_f2b  = (const float*)d_in[36];
  const float* e2_g1   = (const float*)d_in[37];
  const float* e2_b1   = (const float*)d_in[38];
  const float* e2_g2   = (const float*)d_in[39];
  const float* e2_b2   = (const float*)d_in[40];
  const float* ymap2_w = (const float*)d_in[41];
  const float* ymap2_b = (const float*)d_in[42];
  const float* bn_g    = (const float*)d_in[43];
  const float* bn_b    = (const float*)d_in[44];
  const float* d1w     = (const float*)d_in[45];
  const float* d1b     = (const float*)d_in[46];
  const float* d2w     = (const float*)d_in[47];
  const float* d2b     = (const float*)d_in[48];
  const float* d3w     = (const float*)d_in[49];
  const float* d3b     = (const float*)d_in[50];
  const float* d4w     = (const float*)d_in[51];
  const float* d4b     = (const float*)d_in[52];

  float* as_att = (float*)d_ws;                                  // NB*84 f32
  float* mrna   = (float*)((char*)d_ws + (size_t)NB*84*4);       // NB*59 f32
  __bf16* bfb   = (__bf16*)((char*)d_ws + 585728);               // 693248 bf16
  __bf16* xw1B  = bfb;
  __bf16* w1B1  = bfb + 10240;
  __bf16* w2B1  = bfb + 272384;
  __bf16* xw2B  = bfb + 403456;
  __bf16* w1B2  = bfb + 413696;
  __bf16* w2B2  = bfb + 544768;
  __bf16* d1B   = bfb + 610304;
  __bf16* d2B   = bfb + 675840;
  __bf16* d3B   = bfb + 692224;
  float* outp   = (float*)d_out;

  prep_kernel<<<2708, 256, 0, stream>>>(xmap1_w, e1_f1w, e1_f2w, xmap2_w, e2_f1w, e2_f2w,
                                        d1w, d2w, d3w, bfb);

  enc_kernel<<<2*NB, 256, 0, stream>>>(rnafm, rnafm_m,
      xmap1_b, e1_qw, e1_qb, e1_ow, e1_ob, e1_f1b, e1_f2b,
      e1_g1, e1_b1, e1_g2, e1_b2, ymap1_w, ymap1_b, xw1B, w1B1, w2B1,
      xmap2_b, e2_qw, e2_qb, e2_ow, e2_ob, e2_f1b, e2_f2b,
      e2_g1, e2_b1, e2_g2, e2_b2, ymap2_w, ymap2_b, xw2B, w1B2, w2B2,
      as_att, mrna);

  mlp_kernel<<<64, 256, 0, stream>>>(as_att, mrna,
      f_gibbs, f_pssm, f_gcs, f_ssp, f_sse, f_tri, f_di, f_sgl, f_gc,
      bn_g, bn_b, d1b, d2b, d3b, d4w, d4b, d1B, d2B, d3B, outp);
}